// Round 10
// baseline (241.368 us; speedup 1.0000x reference)
//
#include <hip/hip_runtime.h>

#define N_NODES 10000
#define BN_TOT  40000
#define HID     64
#define IN_F    16
#define TCH     32
#define NW      12
#define RSTRIDE 192   // floats per row: [t=3][ch=64] planes at +0B, +256B, +512B

// ---------------- histogram of dst (degree = cnt + 1) ------------------------
__global__ void hist_kernel(const int* __restrict__ dst, int* __restrict__ cnt, int E) {
    int e = blockIdx.x * blockDim.x + threadIdx.x;
    if (e < E) atomicAdd(&cnt[dst[e]], 1);
}

// ---------------- single-block exclusive scan over 10000 bins ----------------
__global__ __launch_bounds__(1024) void scan_kernel(const int* __restrict__ cnt,
                                                    int* __restrict__ row_ptr,
                                                    int* __restrict__ fill_pos,
                                                    float* __restrict__ dinv) {
    __shared__ int part[1024];
    int t = threadIdx.x;
    int base = t * 10;
    int s = 0;
#pragma unroll
    for (int k = 0; k < 10; ++k) {
        int b = base + k;
        if (b < N_NODES) s += cnt[b];
    }
    part[t] = s;
    __syncthreads();
    for (int off = 1; off < 1024; off <<= 1) {
        int v = 0;
        if (t >= off) v = part[t - off];
        __syncthreads();
        part[t] += v;
        __syncthreads();
    }
    int running = (t == 0) ? 0 : part[t - 1];
#pragma unroll
    for (int k = 0; k < 10; ++k) {
        int b = base + k;
        if (b < N_NODES) {
            row_ptr[b]  = running;
            fill_pos[b] = running;
            int c = cnt[b];
            dinv[b] = rsqrtf((float)c + 1.0f);
            running += c;
        }
    }
    if (t == 1023) row_ptr[N_NODES] = part[1023];
}

// ---------------- CSR bucket fill: edge record = {src byte offset, ne} -------
__global__ void fill_kernel(const int* __restrict__ src, const int* __restrict__ dst,
                            const float* __restrict__ dinv,
                            int* __restrict__ fill_pos,
                            int2* __restrict__ edges, int E) {
    int e = blockIdx.x * blockDim.x + threadIdx.x;
    if (e >= E) return;
    int s = src[e], d = dst[e];
    int pos = atomicAdd(&fill_pos[d], 1);
    edges[pos] = make_int2(s * (RSTRIDE * 4), __float_as_int(dinv[s] * dinv[d]));
}

// ---------------- pack conv weights: float4 / float2 per (ic, tc) ------------
// w1p[ic*32+tc] = {c1w[tc][ic][0..2], 0};  w2p[ic*32+tc] = {c2w[tc][ic][0..1]}
__global__ void prep_kernel(const float* __restrict__ c1w, const float* __restrict__ c2w,
                            float4* __restrict__ w1p, float2* __restrict__ w2p) {
    int idx = blockIdx.x * blockDim.x + threadIdx.x;   // 3072 threads
    if (idx < 2048) {
        int tc = idx & 31, ic = idx >> 5;
        const float* p = c1w + tc * 192 + ic * 3;
        w1p[idx] = make_float4(p[0], p[1], p[2], 0.f);
    } else {
        int i2 = idx - 2048;
        int tc = i2 & 31, ic = i2 >> 5;
        const float* p = c2w + tc * 96 + ic * 3;
        w2p[i2] = make_float2(p[0], p[1]);
    }
}

// ---------------- GEMM1 x3: m[bn][t][64] = x_row(16, w=9+t) @ W1 -------------
__global__ __launch_bounds__(256) void gemm1_kernel(const float* __restrict__ x,
                                                    const float* __restrict__ W1,
                                                    float* __restrict__ m) {
    int idx = blockIdx.x * blockDim.x + threadIdx.x;
    int oc = idx & 63;
    int bn = __builtin_amdgcn_readfirstlane(idx >> 6);   // wave-uniform -> s_loads on x
    int b = bn / N_NODES, n = bn - b * N_NODES;
    const float* xb = x + ((size_t)b * NW) * N_NODES * IN_F + (size_t)n * IN_F;
    float s0 = 0.f, s1 = 0.f, s2 = 0.f;
#pragma unroll
    for (int f = 0; f < IN_F; ++f) {
        float wv = W1[f * HID + oc];
        s0 += xb[(size_t)9  * N_NODES * IN_F + f] * wv;
        s1 += xb[(size_t)10 * N_NODES * IN_F + f] * wv;
        s2 += xb[(size_t)11 * N_NODES * IN_F + f] * wv;
    }
    float* mr = m + (size_t)bn * RSTRIDE;
    mr[oc] = s0; mr[64 + oc] = s1; mr[128 + oc] = s2;
}

// ---- gatherA x3: h1 = relu(agg(m1)+dinv^2*m1+b1); m2 = h1 @ W2 --------------
__global__ __launch_bounds__(256) void gatherA_kernel(
        const float* __restrict__ m, const int* __restrict__ row_ptr,
        const int2* __restrict__ edges,
        const float* __restrict__ dinv, const float* __restrict__ b1,
        const float* __restrict__ W2, float* __restrict__ m2) {
    __shared__ float hs[4][3][HID];
    int gid = blockIdx.x * blockDim.x + threadIdx.x;
    int lane = threadIdx.x & 63;
    int wv = threadIdx.x >> 6;
    int row = __builtin_amdgcn_readfirstlane(gid >> 6);  // -> s_loads on CSR
    const int lo0 = lane * 4, lo1 = 256 + lane * 4, lo2 = 512 + lane * 4;
    const char* mrow = (const char*)m + (size_t)row * (RSTRIDE * 4);
    float m0 = *(const float*)(mrow + lo0);
    float m1v = *(const float*)(mrow + lo1);
    float m2v = *(const float*)(mrow + lo2);
    float s0, s1, s2;
    if (row < N_NODES) {
        float dv = dinv[row];
        float sn = dv * dv;
        s0 = sn * m0; s1 = sn * m1v; s2 = sn * m2v;
        int j = row_ptr[row], end = row_ptr[row + 1];
        for (; j + 7 < end; j += 8) {
            const char* q[8]; float w[8];
#pragma unroll
            for (int u = 0; u < 8; ++u) {
                int2 e = edges[j + u];
                q[u] = (const char*)m + e.x;
                w[u] = __int_as_float(e.y);
            }
#pragma unroll
            for (int u = 0; u < 8; ++u) s0 += w[u] * *(const float*)(q[u] + lo0);
#pragma unroll
            for (int u = 0; u < 8; ++u) s1 += w[u] * *(const float*)(q[u] + lo1);
#pragma unroll
            for (int u = 0; u < 8; ++u) s2 += w[u] * *(const float*)(q[u] + lo2);
        }
        for (; j < end; ++j) {
            int2 e = edges[j];
            const char* q = (const char*)m + e.x;
            float w = __int_as_float(e.y);
            s0 += w * *(const float*)(q + lo0);
            s1 += w * *(const float*)(q + lo1);
            s2 += w * *(const float*)(q + lo2);
        }
    } else {
        s0 = m0; s1 = m1v; s2 = m2v;   // deg=1, no in-edges
    }
    float bb = b1[lane];
    hs[wv][0][lane] = fmaxf(s0 + bb, 0.f);
    hs[wv][1][lane] = fmaxf(s1 + bb, 0.f);
    hs[wv][2][lane] = fmaxf(s2 + bb, 0.f);
    __builtin_amdgcn_wave_barrier();
    // W2 matmul: float4 LDS broadcasts + contiguous W2 row loads
    const float4* h0v = (const float4*)&hs[wv][0][0];
    const float4* h1v = (const float4*)&hs[wv][1][0];
    const float4* h2v = (const float4*)&hs[wv][2][0];
    float t0 = 0.f, t1 = 0.f, t2 = 0.f;
#pragma unroll
    for (int ic4 = 0; ic4 < 16; ++ic4) {
        float4 h0 = h0v[ic4], h1 = h1v[ic4], h2 = h2v[ic4];
        float wA = W2[(ic4 * 4 + 0) * HID + lane];
        float wB = W2[(ic4 * 4 + 1) * HID + lane];
        float wC = W2[(ic4 * 4 + 2) * HID + lane];
        float wD = W2[(ic4 * 4 + 3) * HID + lane];
        t0 += h0.x * wA + h0.y * wB + h0.z * wC + h0.w * wD;
        t1 += h1.x * wA + h1.y * wB + h1.z * wC + h1.w * wD;
        t2 += h2.x * wA + h2.y * wB + h2.z * wC + h2.w * wD;
    }
    float* m2r = m2 + (size_t)row * RSTRIDE;
    m2r[lane] = t0; m2r[64 + lane] = t1; m2r[128 + lane] = t2;
}

// ---- gatherBconv: H[t]=relu(agg+self+b2) t=9..11, conv1@10,11 + conv2@11 + fc
__global__ __launch_bounds__(256) void gatherBconv_kernel(
        const float* __restrict__ m, const int* __restrict__ row_ptr,
        const int2* __restrict__ edges,
        const float* __restrict__ dinv, const float* __restrict__ b2,
        const float4* __restrict__ w1p, const float* __restrict__ b1c,
        const float2* __restrict__ w2p, const float* __restrict__ b2c,
        const float* __restrict__ fcw, const float* __restrict__ fcb,
        float* __restrict__ out) {
    __shared__ float hs[4][4][HID];      // planes 0..2 = H@t9,10,11; plane 3 = zeros
    __shared__ float c1s[4][2][TCH];     // conv1 outputs (t = 10,11)
    int gid = blockIdx.x * blockDim.x + threadIdx.x;
    int lane = threadIdx.x & 63;
    int wv = threadIdx.x >> 6;
    int row = __builtin_amdgcn_readfirstlane(gid >> 6);
    const int lo0 = lane * 4, lo1 = 256 + lane * 4, lo2 = 512 + lane * 4;
    const char* mrow = (const char*)m + (size_t)row * (RSTRIDE * 4);
    float m0 = *(const float*)(mrow + lo0);
    float m1v = *(const float*)(mrow + lo1);
    float m2v = *(const float*)(mrow + lo2);
    float s0, s1, s2;
    if (row < N_NODES) {
        float dv = dinv[row];
        float sn = dv * dv;
        s0 = sn * m0; s1 = sn * m1v; s2 = sn * m2v;
        int j = row_ptr[row], end = row_ptr[row + 1];
        for (; j + 7 < end; j += 8) {
            const char* q[8]; float w[8];
#pragma unroll
            for (int u = 0; u < 8; ++u) {
                int2 e = edges[j + u];
                q[u] = (const char*)m + e.x;
                w[u] = __int_as_float(e.y);
            }
#pragma unroll
            for (int u = 0; u < 8; ++u) s0 += w[u] * *(const float*)(q[u] + lo0);
#pragma unroll
            for (int u = 0; u < 8; ++u) s1 += w[u] * *(const float*)(q[u] + lo1);
#pragma unroll
            for (int u = 0; u < 8; ++u) s2 += w[u] * *(const float*)(q[u] + lo2);
        }
        for (; j < end; ++j) {
            int2 e = edges[j];
            const char* q = (const char*)m + e.x;
            float w = __int_as_float(e.y);
            s0 += w * *(const float*)(q + lo0);
            s1 += w * *(const float*)(q + lo1);
            s2 += w * *(const float*)(q + lo2);
        }
    } else {
        s0 = m0; s1 = m1v; s2 = m2v;
    }
    float bb = b2[lane];
    hs[wv][0][lane] = fmaxf(s0 + bb, 0.f);   // H @ t=9
    hs[wv][1][lane] = fmaxf(s1 + bb, 0.f);   // H @ t=10
    hs[wv][2][lane] = fmaxf(s2 + bb, 0.f);   // H @ t=11
    hs[wv][3][lane] = 0.f;                   // zero plane (pad tap)
    __builtin_amdgcn_wave_barrier();

    // ---- conv1: lane (pos,tc) computes c1[10+pos][tc]; float4 weights + hs --
    int pos = lane >> 5, tc = lane & 31;
    const float4* hAv = (const float4*)&hs[wv][pos][0];
    const float4* hBv = (const float4*)&hs[wv][pos + 1][0];
    const float4* hCv = (const float4*)&hs[wv][(pos == 0) ? 2 : 3][0];  // pad -> zeros
    float acc = b1c[tc];
#pragma unroll
    for (int ic4 = 0; ic4 < 16; ++ic4) {
        float4 hA = hAv[ic4], hB = hBv[ic4], hC = hCv[ic4];
        float4 wa = w1p[(ic4 * 4 + 0) * 32 + tc];
        float4 wb = w1p[(ic4 * 4 + 1) * 32 + tc];
        float4 wc = w1p[(ic4 * 4 + 2) * 32 + tc];
        float4 wd = w1p[(ic4 * 4 + 3) * 32 + tc];
        acc += hA.x * wa.x + hB.x * wa.y + hC.x * wa.z;
        acc += hA.y * wb.x + hB.y * wb.y + hC.y * wb.z;
        acc += hA.z * wc.x + hB.z * wc.y + hC.z * wc.z;
        acc += hA.w * wd.x + hB.w * wd.y + hC.w * wd.z;
    }
    c1s[wv][pos][tc] = fmaxf(acc, 0.f);
    __builtin_amdgcn_wave_barrier();

    // ---- conv2 @ t=11 (+relu, *fcw) on lanes 0..31; reduce; fc ----
    float r = 0.f;
    if (pos == 0) {
        const float4* cAv = (const float4*)&c1s[wv][0][0];
        const float4* cBv = (const float4*)&c1s[wv][1][0];
        float a2 = b2c[tc];
#pragma unroll
        for (int ic4 = 0; ic4 < 8; ++ic4) {
            float4 cA = cAv[ic4], cB = cBv[ic4];
            float2 w0 = w2p[(ic4 * 4 + 0) * 32 + tc];
            float2 w1 = w2p[(ic4 * 4 + 1) * 32 + tc];
            float2 w2v = w2p[(ic4 * 4 + 2) * 32 + tc];
            float2 w3 = w2p[(ic4 * 4 + 3) * 32 + tc];
            a2 += cA.x * w0.x + cB.x * w0.y;
            a2 += cA.y * w1.x + cB.y * w1.y;
            a2 += cA.z * w2v.x + cB.z * w2v.y;
            a2 += cA.w * w3.x + cB.w * w3.y;
        }
        r = fmaxf(a2, 0.f) * fcw[tc];
    }
#pragma unroll
    for (int off = 16; off > 0; off >>= 1) r += __shfl_down(r, off);
    if (lane == 0) out[row] = r + fcb[0];
}

extern "C" void kernel_launch(void* const* d_in, const int* in_sizes, int n_in,
                              void* d_out, int out_size, void* d_ws, size_t ws_size,
                              hipStream_t stream) {
    const float* x   = (const float*)d_in[0];
    const int*   ei  = (const int*)d_in[1];
    const float* W1  = (const float*)d_in[2];
    const float* b1  = (const float*)d_in[3];
    const float* W2  = (const float*)d_in[4];
    const float* b2  = (const float*)d_in[5];
    const float* c1w = (const float*)d_in[6];
    const float* c1b = (const float*)d_in[7];
    const float* c2w = (const float*)d_in[8];
    const float* c2b = (const float*)d_in[9];
    const float* fcw = (const float*)d_in[10];
    const float* fcb = (const float*)d_in[11];
    float* out = (float*)d_out;

    const int E = in_sizes[1] / 2;
    const int* src = ei;
    const int* dst = ei + E;

    // ---- workspace layout (mA offset is 768B-aligned: 691200 floats) ----
    const size_t S3 = (size_t)BN_TOT * RSTRIDE;    // 7,680,000 floats per m-buffer
    int*    cnt      = (int*)d_ws;                 // 10240
    int*    row_ptr  = cnt + 10240;                // 10240
    int*    fill_pos = row_ptr + 10240;            // 10240
    int2*   edges    = (int2*)(fill_pos + 10240);  // E records (8 B each)
    float*  dinv     = (float*)(edges + E);        // 10240
    float4* w1p      = (float4*)(dinv + 10240);    // 2048 float4 (8192 floats)
    float2* w2p      = (float2*)(w1p + 2048);      // 1024 float2 (2048 floats)
    float*  mA       = (float*)(w2p + 1024);       // S3
    float*  mB       = mA + S3;                    // S3

    // ---- CSR build + weight packing ----
    hipMemsetAsync(cnt, 0, N_NODES * sizeof(int), stream);
    hist_kernel<<<(E + 255) / 256, 256, 0, stream>>>(dst, cnt, E);
    scan_kernel<<<1, 1024, 0, stream>>>(cnt, row_ptr, fill_pos, dinv);
    fill_kernel<<<(E + 255) / 256, 256, 0, stream>>>(src, dst, dinv, fill_pos, edges, E);
    prep_kernel<<<12, 256, 0, stream>>>(c1w, c2w, w1p, w2p);

    const int NT = BN_TOT * HID;                   // 2,560,000 threads = 10000 blocks
    gemm1_kernel <<<NT / 256, 256, 0, stream>>>(x, W1, mA);
    gatherA_kernel<<<NT / 256, 256, 0, stream>>>(mA, row_ptr, edges, dinv, b1, W2, mB);
    gatherBconv_kernel<<<NT / 256, 256, 0, stream>>>(mB, row_ptr, edges, dinv, b2,
                                                     w1p, c1b, w2p, c2b, fcw, fcb, out);
}